// Round 12
// baseline (285.999 us; speedup 1.0000x reference)
//
#include <hip/hip_runtime.h>
#include <hip/hip_bf16.h>

#define A_ 8
#define B_ 4096
#define OBS_ 512
#define ACT_ 64
#define H_ 1024
#define G_ 64
#define N_ 10000
#define E_ 40000

using bf16 = __hip_bfloat16;
typedef __attribute__((ext_vector_type(8))) short short8;
typedef __attribute__((ext_vector_type(4))) float f32x4;

__device__ __forceinline__ float wsum(float v) {
#pragma unroll
  for (int off = 32; off >= 1; off >>= 1) v += __shfl_xor(v, off, 64);
  return v;
}

__device__ __forceinline__ void storeC(float* p, float v) { *p = v; }
__device__ __forceinline__ void storeC(bf16* p, float v) { *p = __float2bfloat16(v); }

__device__ __forceinline__ unsigned short f2bu(float x) {
  bf16 h = __float2bfloat16(x);
  unsigned short u;
  __builtin_memcpy(&u, &h, 2);
  return u;
}

__device__ __forceinline__ void gload_lds16(const bf16* g, const void* lds_uniform) {
  __builtin_amdgcn_global_load_lds(
      (const __attribute__((address_space(1))) unsigned int*)g,
      (__attribute__((address_space(3))) unsigned int*)lds_uniform, 16, 0, 0);
}

template <int N>
__device__ __forceinline__ void waitvm() {
#define WV_CASE(n) if constexpr (N == n) asm volatile("s_waitcnt vmcnt(" #n ")" ::: "memory");
  WV_CASE(0) WV_CASE(1) WV_CASE(2) WV_CASE(3) WV_CASE(4) WV_CASE(5) WV_CASE(6) WV_CASE(7)
  WV_CASE(8) WV_CASE(9) WV_CASE(10) WV_CASE(12) WV_CASE(16)
  static_assert(N <= 16, "vmcnt too large");
#undef WV_CASE
}

// ======= prep_k: conv_joint (blocks 0-8191) + 5x wtrans (8192-14911) + gnn_l0 (14912-17411) ===
__global__ __launch_bounds__(256) void prep_k(
    const float* __restrict__ obs, bf16* __restrict__ joint,
    const float* __restrict__ Wp1, bf16* __restrict__ Wp1t,
    const float* __restrict__ Wp2, bf16* __restrict__ Wp2t,
    const float* __restrict__ Wp3, bf16* __restrict__ Wp3t,
    const float* __restrict__ Wv1, bf16* __restrict__ Wv1t,
    const float* __restrict__ Wv2, bf16* __restrict__ Wv2t,
    const int* __restrict__ node_types, const int* __restrict__ node_agents,
    const float* __restrict__ type_embed, const float* __restrict__ gagent_embed,
    const float* __restrict__ W_l0, const float* __restrict__ b_l0,
    const float* __restrict__ g_l0, const float* __restrict__ be_l0,
    float* __restrict__ h0, float* __restrict__ agg, float* __restrict__ deg) {
  __shared__ float shb[32 * 33];
  const int bid = blockIdx.x, tid = threadIdx.x;
  if (bid < 8192) {
    size_t i = ((size_t)bid * 256 + tid) * 8;
    int a = (int)(i >> 21);
    int rem = (int)(i & ((1u << 21) - 1));
    int b = rem >> 9, k = rem & 511;
    const float* p = obs + i;
    short8 o;
#pragma unroll
    for (int t = 0; t < 8; t++) o[t] = (short)f2bu(p[t]);
    *(short8*)(joint + (size_t)b * 4096 + a * 512 + k) = o;
  } else if (bid < 14912) {
    int b = bid - 8192;
    const float* W;
    bf16* Wt;
    int K, N;
    if (b < 512) { W = Wp1; Wt = Wp1t; K = 512; N = 1024; }
    else if (b < 1536) { W = Wp2; Wt = Wp2t; K = 1024; N = 1024; b -= 512; }
    else if (b < 1600) { W = Wp3; Wt = Wp3t; K = 1024; N = 64; b -= 1536; }
    else if (b < 5696) { W = Wv1; Wt = Wv1t; K = 4096; N = 1024; b -= 1600; }
    else { W = Wv2; Wt = Wv2t; K = 1024; N = 1024; b -= 5696; }
    int nx = N >> 5;
    int n0 = (b % nx) * 32, k0 = (b / nx) * 32;
    int tx = tid & 31, ty = tid >> 5;
    float(*t2)[33] = (float(*)[33])shb;
#pragma unroll
    for (int r = ty; r < 32; r += 8) t2[r][tx] = W[(size_t)(k0 + r) * N + n0 + tx];
    __syncthreads();
#pragma unroll
    for (int r = ty; r < 32; r += 8)
      Wt[(size_t)(n0 + r) * K + k0 + tx] = __float2bfloat16(t2[tx][r]);
  } else {
    int nb = bid - 14912;
    int w = tid >> 6, t = tid & 63;
    int n = nb * 4 + w;
    float* xx = shb + w * 64;
    int ty2 = node_types[n], ag = node_agents[n];
    xx[t] = (t < 32) ? type_embed[ty2 * 32 + t] : gagent_embed[ag * 32 + (t - 32)];
    agg[(size_t)n * 64 + t] = 0.f;
    if (t == 0) deg[n] = 0.f;
    __syncthreads();
    float acc = b_l0[t];
#pragma unroll 8
    for (int i = 0; i < 64; i++) acc += xx[i] * W_l0[i * 64 + t];
    acc = fmaxf(acc, 0.f);
    float m = wsum(acc) * (1.f / 64.f);
    float d = acc - m;
    float v = wsum(d * d) * (1.f / 64.f);
    h0[(size_t)n * 64 + t] = d * rsqrtf(v + 1e-5f) * g_l0[t] + be_l0[t];
  }
}

__global__ void edge_k(const int* __restrict__ edges, const float* __restrict__ h0,
                       float* __restrict__ agg, float* __restrict__ deg) {
  int idx = blockIdx.x * 256 + threadIdx.x;
  if (idx >= E_ * 64) return;
  int e = idx >> 6, c = idx & 63;
  int s = edges[e * 2 + 0], d = edges[e * 2 + 1];
  atomicAdd(&agg[(size_t)d * 64 + c], h0[(size_t)s * 64 + c]);
  atomicAdd(&agg[(size_t)s * 64 + c], h0[(size_t)d * 64 + c]);
  if (c == 0) { atomicAdd(&deg[d], 1.f); atomicAdd(&deg[s], 1.f); }
}

__global__ __launch_bounds__(256) void gnn_l1_k(
    const float* __restrict__ h0, const float* __restrict__ agg, const float* __restrict__ deg,
    const float* __restrict__ W, const float* __restrict__ b, const float* __restrict__ g,
    const float* __restrict__ be, float* __restrict__ h1) {
  __shared__ float x[4][128];
  int w = threadIdx.x >> 6, t = threadIdx.x & 63;
  int n = blockIdx.x * 4 + w;
  x[w][t] = h0[(size_t)n * 64 + t];
  x[w][64 + t] = agg[(size_t)n * 64 + t] / fmaxf(deg[n], 1.0f);
  __syncthreads();
  float acc = b[t];
#pragma unroll 8
  for (int i = 0; i < 128; i++) acc += x[w][i] * W[i * 64 + t];
  acc = fmaxf(acc, 0.f);
  float m = wsum(acc) * (1.f / 64.f);
  float d = acc - m;
  float v = wsum(d * d) * (1.f / 64.f);
  h1[(size_t)n * 64 + t] = d * rsqrtf(v + 1e-5f) * g[t] + be[t];
}

__global__ void colmean_k(const float* __restrict__ h1, float* __restrict__ meanv) {
  int c = blockIdx.x, t = threadIdx.x;
  float s = 0.f;
  for (int n = t; n < N_; n += 256) s += h1[(size_t)n * 64 + c];
  __shared__ float red[256];
  red[t] = s;
  __syncthreads();
  for (int off = 128; off >= 1; off >>= 1) {
    if (t < off) red[t] += red[t + off];
    __syncthreads();
  }
  if (t == 0) meanv[c] = red[0] / (float)N_;
}

__global__ void fused_bias_k(const float* __restrict__ meanv, const float* __restrict__ Wgp,
                             const float* __restrict__ bgp, const float* __restrict__ agent_embed,
                             const float* __restrict__ Wp1, const float* __restrict__ bp1,
                             const float* __restrict__ Wv1, const float* __restrict__ bv1,
                             const float* __restrict__ bv3,
                             float* __restrict__ biasA, float* __restrict__ biasV,
                             float* __restrict__ value) {
  __shared__ float ge[64];
  int t = threadIdx.x;
  int gidx = blockIdx.x * 256 + t;
  if (gidx < B_) value[gidx] = bv3[0];
  if (t < 64) {
    float s = bgp[t];
    for (int g2 = 0; g2 < 64; g2++) s += meanv[g2] * Wgp[g2 * 64 + t];
    ge[t] = s;
  }
  __syncthreads();
  int blk = blockIdx.x;
  if (blk < 32) {
    int idx = blk * 256 + t;
    int a = idx >> 10, o = idx & 1023;
    float s = bp1[o];
    for (int g2 = 0; g2 < 64; g2++) s += ge[g2] * Wp1[(size_t)(512 + g2) * 1024 + o];
    for (int e = 0; e < 16; e++) s += agent_embed[a * 16 + e] * Wp1[(size_t)(576 + e) * 1024 + o];
    biasA[idx] = s;
  } else {
    int o = (blk - 32) * 256 + t;
    float s = bv1[o];
    for (int g2 = 0; g2 < 64; g2++) s += ge[g2] * Wv1[(size_t)(4096 + g2) * 1024 + o];
    biasV[o] = s;
  }
}

// ======== g12_k: 256x256, BK=32, QUAD buffer (4 x 32 KB), stage distance 3, vmcnt(8) =========
// Per K-tile: 2 phases x {ds_reads, 2 gloads of tile t+3, barrier, 16 MFMA (setprio), barrier}.
// End-of-tile wait vmcnt(8): drains tile t+1 (issued 2 tiles earlier, ~4-6 phases of cover ~
// HBM latency), leaves t+2/t+3 (8 loads) in flight. Drain: vmcnt(8)->4->0.
// LDS rows = 64 B (4 slots of 16 B); XOR slot swizzle slot ^= (row>>1)&3 -> 2-way (free).
#define BARR()                        \
  asm volatile("" ::: "memory");      \
  __builtin_amdgcn_s_barrier();       \
  asm volatile("" ::: "memory")

#define RD8(off) (*(const short8*)(sb + (off)))

#define MMQ(FI0)                                                                     \
  __builtin_amdgcn_s_setprio(1);                                                     \
  acc[FI0 + 0][0] = __builtin_amdgcn_mfma_f32_16x16x32_bf16(a0, b0, acc[FI0 + 0][0], 0, 0, 0); \
  acc[FI0 + 0][1] = __builtin_amdgcn_mfma_f32_16x16x32_bf16(a0, b1, acc[FI0 + 0][1], 0, 0, 0); \
  acc[FI0 + 0][2] = __builtin_amdgcn_mfma_f32_16x16x32_bf16(a0, b2, acc[FI0 + 0][2], 0, 0, 0); \
  acc[FI0 + 0][3] = __builtin_amdgcn_mfma_f32_16x16x32_bf16(a0, b3, acc[FI0 + 0][3], 0, 0, 0); \
  acc[FI0 + 1][0] = __builtin_amdgcn_mfma_f32_16x16x32_bf16(a1, b0, acc[FI0 + 1][0], 0, 0, 0); \
  acc[FI0 + 1][1] = __builtin_amdgcn_mfma_f32_16x16x32_bf16(a1, b1, acc[FI0 + 1][1], 0, 0, 0); \
  acc[FI0 + 1][2] = __builtin_amdgcn_mfma_f32_16x16x32_bf16(a1, b2, acc[FI0 + 1][2], 0, 0, 0); \
  acc[FI0 + 1][3] = __builtin_amdgcn_mfma_f32_16x16x32_bf16(a1, b3, acc[FI0 + 1][3], 0, 0, 0); \
  acc[FI0 + 2][0] = __builtin_amdgcn_mfma_f32_16x16x32_bf16(a2, b0, acc[FI0 + 2][0], 0, 0, 0); \
  acc[FI0 + 2][1] = __builtin_amdgcn_mfma_f32_16x16x32_bf16(a2, b1, acc[FI0 + 2][1], 0, 0, 0); \
  acc[FI0 + 2][2] = __builtin_amdgcn_mfma_f32_16x16x32_bf16(a2, b2, acc[FI0 + 2][2], 0, 0, 0); \
  acc[FI0 + 2][3] = __builtin_amdgcn_mfma_f32_16x16x32_bf16(a2, b3, acc[FI0 + 2][3], 0, 0, 0); \
  acc[FI0 + 3][0] = __builtin_amdgcn_mfma_f32_16x16x32_bf16(a3, b0, acc[FI0 + 3][0], 0, 0, 0); \
  acc[FI0 + 3][1] = __builtin_amdgcn_mfma_f32_16x16x32_bf16(a3, b1, acc[FI0 + 3][1], 0, 0, 0); \
  acc[FI0 + 3][2] = __builtin_amdgcn_mfma_f32_16x16x32_bf16(a3, b2, acc[FI0 + 3][2], 0, 0, 0); \
  acc[FI0 + 3][3] = __builtin_amdgcn_mfma_f32_16x16x32_bf16(a3, b3, acc[FI0 + 3][3], 0, 0, 0); \
  __builtin_amdgcn_s_setprio(0)

template <int AMODE, int BIASMODE, bool RELU, typename TC>
__launch_bounds__(512, 1)
__global__ void g12_k(const bf16* __restrict__ Ap, const bf16* __restrict__ Bt,
                      const float* __restrict__ biasp, TC* __restrict__ Cp,
                      int M, int N, int K) {
  constexpr int TBUF = 32768;       // (256 A-rows + 256 B-rows) x 64 B
  __shared__ char smem[4 * TBUF];   // 128 KB quad buffer

  const int tid = threadIdx.x;
  const int wid = tid >> 6, lane = tid & 63;
  const int wm = wid >> 2, wn = wid & 3;
  const int l15 = lane & 15;

  // T1: bijective XCD swizzle (nwg % 8 == 0)
  const int nwg = gridDim.x * gridDim.y;
  int fid = blockIdx.y * gridDim.x + blockIdx.x;
  int swz = (fid & 7) * (nwg >> 3) + (fid >> 3);
  const int m0 = (swz / gridDim.x) * 256;
  const int n0 = (swz % gridDim.x) * 256;

  f32x4 acc[8][4];
#pragma unroll
  for (int i = 0; i < 8; i++)
#pragma unroll
    for (int j = 0; j < 4; j++) acc[i][j] = (f32x4){0.f, 0.f, 0.f, 0.f};

  // staging: 4 gload groups, each 128 rows x 64 B; thread -> row = g*128 + tid>>2, slot = tid&3,
  // pre-swizzled source chunk c = slot ^ ((row>>1)&3). LDS stays linear (lane*16 within wave).
  const bf16* pg[4];
  {
    int srow = tid >> 2;
    int c = (tid & 3) ^ ((srow >> 1) & 3);
    int rA0 = m0 + srow, rA1 = m0 + 128 + srow;
    if (AMODE == 0) {
      pg[0] = Ap + (size_t)rA0 * K + c * 8;
      pg[1] = Ap + (size_t)rA1 * K + c * 8;
    } else {
      pg[0] = Ap + (((size_t)(rA0 & (B_ - 1))) << 12) + ((size_t)(rA0 >> 12) << 9) + c * 8;
      pg[1] = Ap + (((size_t)(rA1 & (B_ - 1))) << 12) + ((size_t)(rA1 >> 12) << 9) + c * 8;
    }
    pg[2] = Bt + (size_t)(n0 + srow) * K + c * 8;
    pg[3] = Bt + (size_t)(n0 + 128 + srow) * K + c * 8;
  }

  // fragment byte offsets (read-side applies the same XOR): frag i at off + i*1024
  const int rA = wm * 128 + l15;
  const int offA = rA * 64 + (((lane >> 4) ^ ((rA >> 1) & 3))) * 16;
  const int rB = wn * 64 + l15;
  const int offB = 16384 + rB * 64 + (((lane >> 4) ^ ((rB >> 1) & 3))) * 16;

#define STG(g, buf)                                                    \
  {                                                                    \
    gload_lds16(pg[g], smem + (buf) * TBUF + (g) * 8192 + wid * 1024); \
    pg[g] += 32;                                                       \
  }

  // prologue: stage tiles 0,1,2 into bufs 0,1,2 (12 loads); drain tile 0 (leave 8)
#pragma unroll
  for (int q = 0; q < 3; ++q) { STG(0, q) STG(1, q) STG(2, q) STG(3, q) }
  waitvm<8>();
  BARR();

  const int nt = K >> 5;  // K-tiles of 32; requires nt >= 4
  for (int t = 0; t < nt; ++t) {
    const char* sb = smem + (t & 3) * TBUF;
    const int ob = (t + 3) & 3;
    const bool stg = (t + 3) < nt;
    short8 a0, a1, a2, a3, b0, b1, b2, b3;
    // ---- phase 0: A frags 0-3 + B frags 0-3
    a0 = RD8(offA + 0 * 1024); a1 = RD8(offA + 1 * 1024);
    a2 = RD8(offA + 2 * 1024); a3 = RD8(offA + 3 * 1024);
    b0 = RD8(offB + 0 * 1024); b1 = RD8(offB + 1 * 1024);
    b2 = RD8(offB + 2 * 1024); b3 = RD8(offB + 3 * 1024);
    if (stg) { STG(0, ob) STG(1, ob) }
    BARR();
    MMQ(0);
    BARR();
    // ---- phase 1: A frags 4-7 (reuse b0..b3)
    a0 = RD8(offA + 4 * 1024); a1 = RD8(offA + 5 * 1024);
    a2 = RD8(offA + 6 * 1024); a3 = RD8(offA + 7 * 1024);
    if (stg) { STG(2, ob) STG(3, ob) }
    BARR();
    MMQ(4);
    // end-of-tile wait: drain tile t+1; keep t+2/t+3 (8 loads) in flight
    if (t + 4 <= nt) {          // staged this tile (t <= nt-4): 12 outstanding -> 8
      waitvm<8>();
    } else if (t + 3 == nt) {   // t == nt-3: outstanding = t+1,t+2 (8) -> 4
      waitvm<4>();
    } else if (t + 2 == nt) {   // t == nt-2: outstanding = t+1 (4) -> 0
      waitvm<0>();
    }                           // t == nt-1: nothing outstanding
    BARR();
  }
#undef STG

  // epilogue: C/D layout col=lane&15, row=(lane>>4)*4+reg
#pragma unroll
  for (int i = 0; i < 8; ++i) {
    int rb = m0 + wm * 128 + i * 16 + (lane >> 4) * 4;
#pragma unroll
    for (int j = 0; j < 4; ++j) {
      int col = n0 + wn * 64 + j * 16 + l15;
#pragma unroll
      for (int r = 0; r < 4; r++) {
        int row = rb + r;
        float bias = (BIASMODE == 0) ? biasp[col] : biasp[((row >> 12) << 10) + col];
        float v = acc[i][j][r] + bias;
        if (RELU) v = fmaxf(v, 0.f);
        storeC(&Cp[(size_t)row * N + col], v);
      }
    }
  }
}

// ---------------- MFMA GEMM: DEPTH-deep multi-buffer pipeline, counted vmcnt ----------------
// VOUT=1: instead of storing C, accumulate value[row] += relu(C[row,:]+bias) . Wv3 (fused V3)
template <int FM, int FN, int WAVES_M, int WAVES_N, int DEPTH, int AMODE, int BIASMODE, bool RELU,
          typename TC, int VOUT = 0>
__launch_bounds__(WAVES_M * WAVES_N * 64, 2)
__global__ void pgemm_k(const bf16* __restrict__ Ap, const bf16* __restrict__ Bt,
                        const float* __restrict__ biasp, TC* __restrict__ Cp,
                        int M, int N, int K,
                        const float* __restrict__ Wv3 = nullptr,
                        float* __restrict__ vout = nullptr) {
  constexpr int NTHR = WAVES_M * WAVES_N * 64;
  constexpr int AR = WAVES_M * FM * 16;
  constexpr int BR = WAVES_N * FN * 16;
  constexpr int RPG = NTHR / 4;
  constexpr int AG = AR / RPG;
  constexpr int BG = BR / RPG;
  constexpr int G = AG + BG;
  constexpr int GRP = NTHR * 16;
  constexpr int ABYTES = AR * 64;
  constexpr int SBUF = (AR + BR) * 64;
  constexpr int NB = DEPTH + 1;
  __shared__ char smem[NB * SBUF];

  const int tid = threadIdx.x;
  const int wid = tid >> 6, lane = tid & 63;
  const int wm = wid / WAVES_N, wn = wid % WAVES_N;
  const int l15 = lane & 15;

  const int nwg = gridDim.x * gridDim.y;
  int fid = blockIdx.y * gridDim.x + blockIdx.x;
  int swz = (fid & 7) * (nwg >> 3) + (fid >> 3);
  const int m0 = (swz / gridDim.x) * AR;
  const int n0 = (swz % gridDim.x) * BR;

  f32x4 acc[FM][FN];
#pragma unroll
  for (int i = 0; i < FM; i++)
#pragma unroll
    for (int j = 0; j < FN; j++) acc[i][j] = (f32x4){0.f, 0.f, 0.f, 0.f};

  const bf16* pa[AG];
  const bf16* pb[BG];
  {
    int row = tid >> 2;
    int c = (tid & 3) ^ ((tid >> 3) & 3);
#pragma unroll
    for (int q = 0; q < AG; ++q) {
      int r = m0 + q * RPG + row;
      if (AMODE == 0)
        pa[q] = Ap + (size_t)r * K + c * 8;
      else
        pa[q] = Ap + (((size_t)(r & (B_ - 1))) << 12) + ((size_t)(r >> 12) << 9) + c * 8;
    }
#pragma unroll
    for (int q = 0; q < BG; ++q) {
      int r = n0 + q * RPG + row;
      pb[q] = Bt + (size_t)r * K + c * 8;
    }
  }

  const int cA = (lane >> 4) ^ ((l15 >> 1) & 3);
  const int offA0 = (wm * FM * 16 + l15) * 64 + cA * 16;
  const int offB0 = ABYTES + (wn * FN * 16 + l15) * 64 + cA * 16;

  auto stage = [&](int buf) {
    char* base = smem + buf * SBUF;
#pragma unroll
    for (int q = 0; q < AG; ++q) {
      gload_lds16(pa[q], base + q * GRP + wid * 1024);
      pa[q] += 32;
    }
#pragma unroll
    for (int q = 0; q < BG; ++q) {
      gload_lds16(pb[q], base + ABYTES + q * GRP + wid * 1024);
      pb[q] += 32;
    }
  };

  auto comp = [&](int buf) {
    const char* sb = smem + buf * SBUF;
    short8 bfr[FN];
#pragma unroll
    for (int j = 0; j < FN; ++j) bfr[j] = *(const short8*)(sb + offB0 + j * 1024);
    constexpr int FH = (FM > 4) ? FM / 2 : FM;
#pragma unroll
    for (int h = 0; h < FM / FH; ++h) {
      short8 afr[FH];
#pragma unroll
      for (int i = 0; i < FH; ++i) afr[i] = *(const short8*)(sb + offA0 + (h * FH + i) * 1024);
      __builtin_amdgcn_s_setprio(1);
#pragma unroll
      for (int i = 0; i < FH; ++i)
#pragma unroll
        for (int j = 0; j < FN; ++j)
          acc[h * FH + i][j] =
              __builtin_amdgcn_mfma_f32_16x16x32_bf16(afr[i], bfr[j], acc[h * FH + i][j], 0, 0, 0);
      __builtin_amdgcn_s_setprio(0);
    }
  };

  const int nt = K >> 5;
#pragma unroll
  for (int q = 0; q < DEPTH; ++q) stage(q);
  int cbuf = 0, sbi = DEPTH;
  for (int T = 0; T < nt - DEPTH; ++T) {
    stage(sbi);
    if (++sbi == NB) sbi = 0;
    waitvm<DEPTH * G>();
    __builtin_amdgcn_s_barrier();
    asm volatile("" ::: "memory");
    comp(cbuf);
    if (++cbuf == NB) cbuf = 0;
    asm volatile("" ::: "memory");
    __builtin_amdgcn_s_barrier();
  }
#define DRAIN(d)                       \
  {                                    \
    waitvm<(d) * G>();                 \
    __builtin_amdgcn_s_barrier();      \
    asm volatile("" ::: "memory");     \
    comp(cbuf);                        \
    if (++cbuf == NB) cbuf = 0;        \
    asm volatile("" ::: "memory");     \
  }
  if constexpr (DEPTH == 4) { DRAIN(3) DRAIN(2) }
  DRAIN(1)
  DRAIN(0)
#undef DRAIN

#pragma unroll
  for (int i = 0; i < FM; ++i) {
    int rb = m0 + wm * FM * 16 + i * 16 + (lane >> 4) * 4;
    if constexpr (VOUT) {
#pragma unroll
      for (int r = 0; r < 4; r++) {
        int row = rb + r;
        float s = 0.f;
#pragma unroll
        for (int j = 0; j < FN; ++j) {
          int col = n0 + wn * FN * 16 + j * 16 + l15;
          float v = acc[i][j][r] + biasp[col];
          if (RELU) v = fmaxf(v, 0.f);
          s += v * Wv3[col];
        }
        s += __shfl_xor(s, 1, 64);
        s += __shfl_xor(s, 2, 64);
        s += __shfl_xor(s, 4, 64);
        s += __shfl_xor(s, 8, 64);
        if (l15 == 0) atomicAdd(&vout[row], s);
      }
    } else {
#pragma unroll
      for (int j = 0; j < FN; ++j) {
        int col = n0 + wn * FN * 16 + j * 16 + l15;
#pragma unroll
        for (int r = 0; r < 4; r++) {
          int row = rb + r;
          float bias = (BIASMODE == 0) ? biasp[col] : biasp[((row >> 12) << 10) + col];
          float v = acc[i][j][r] + bias;
          if (RELU) v = fmaxf(v, 0.f);
          storeC(&Cp[(size_t)row * N + col], v);
        }
      }
    }
  }
}

extern "C" void kernel_launch(void* const* d_in, const int* in_sizes, int n_in,
                              void* d_out, int out_size, void* d_ws, size_t ws_size,
                              hipStream_t stream) {
  const float* obs = (const float*)d_in[0];
  const int* node_types = (const int*)d_in[1];
  const int* node_agents = (const int*)d_in[2];
  const int* edges = (const int*)d_in[3];
  const float* type_embed = (const float*)d_in[4];
  const float* gagent_embed = (const float*)d_in[5];
  const float* W_l0 = (const float*)d_in[6];
  const float* b_l0 = (const float*)d_in[7];
  const float* g_l0 = (const float*)d_in[8];
  const float* be_l0 = (const float*)d_in[9];
  const float* W_l1 = (const float*)d_in[10];
  const float* b_l1 = (const float*)d_in[11];
  const float* g_l1 = (const float*)d_in[12];
  const float* be_l1 = (const float*)d_in[13];
  const float* W_gp = (const float*)d_in[14];
  const float* b_gp = (const float*)d_in[15];
  const float* agent_embed = (const float*)d_in[16];
  const float* Wp1 = (const float*)d_in[17];
  const float* bp1 = (const float*)d_in[18];
  const float* Wp2 = (const float*)d_in[19];
  const float* bp2 = (const float*)d_in[20];
  const float* Wp3 = (const float*)d_in[21];
  const float* bp3 = (const float*)d_in[22];
  const float* Wv1 = (const float*)d_in[23];
  const float* bv1 = (const float*)d_in[24];
  const float* Wv2 = (const float*)d_in[25];
  const float* bv2 = (const float*)d_in[26];
  const float* Wv3 = (const float*)d_in[27];
  const float* bv3 = (const float*)d_in[28];

  char* wsp = (char*)d_ws;
  auto alloc = [&](size_t bytes) {
    char* p = wsp;
    wsp += (bytes + 255) & ~(size_t)255;
    return p;
  };
  float* h0 = (float*)alloc((size_t)N_ * 64 * 4);
  float* agg = (float*)alloc((size_t)N_ * 64 * 4);
  float* deg = (float*)alloc((size_t)N_ * 4);
  float* h1 = (float*)alloc((size_t)N_ * 64 * 4);
  float* meanv = (float*)alloc(64 * 4);
  float* biasA = (float*)alloc(8 * 1024 * 4);
  float* biasV = (float*)alloc(1024 * 4);
  bf16* joint = (bf16*)alloc((size_t)4096 * 4096 * 2);
  bf16* Wp1t = (bf16*)alloc((size_t)1024 * 512 * 2);
  bf16* Wp2t = (bf16*)alloc((size_t)1024 * 1024 * 2);
  bf16* Wp3t = (bf16*)alloc((size_t)64 * 1024 * 2);
  bf16* Wv1t = (bf16*)alloc((size_t)1024 * 4096 * 2);
  bf16* Wv2t = (bf16*)alloc((size_t)1024 * 1024 * 2);
  bf16* C1 = (bf16*)alloc((size_t)32768 * 1024 * 2);
  bf16* C2 = (bf16*)alloc((size_t)32768 * 1024 * 2);
  bf16* hv = (bf16*)alloc((size_t)4096 * 1024 * 2);

  float* logits = (float*)d_out;
  float* value = (float*)d_out + (size_t)A_ * B_ * ACT_;

  // prep: conv_joint + 5x wtrans + gnn_l0 (co-scheduled in one launch)
  prep_k<<<17412, 256, 0, stream>>>(obs, joint, Wp1, Wp1t, Wp2, Wp2t, Wp3, Wp3t, Wv1, Wv1t, Wv2,
                                    Wv2t, node_types, node_agents, type_embed, gagent_embed, W_l0,
                                    b_l0, g_l0, be_l0, h0, agg, deg);
  edge_k<<<(E_ * 64) / 256, 256, 0, stream>>>(edges, h0, agg, deg);
  gnn_l1_k<<<N_ / 4, 256, 0, stream>>>(h0, agg, deg, W_l1, b_l1, g_l1, be_l1, h1);
  colmean_k<<<64, 256, 0, stream>>>(h1, meanv);
  fused_bias_k<<<36, 256, 0, stream>>>(meanv, W_gp, b_gp, agent_embed, Wp1, bp1, Wv1, bv1, bv3,
                                       biasA, biasV, value);

  // P1: C1 = relu(obs2d @ Wp1[0:512] + biasA[agent])  M=32768 N=1024 K=512, g12 256x256 BK32
  g12_k<1, 1, true, bf16>
      <<<dim3(4, 128), 512, 0, stream>>>(joint, Wp1t, biasA, C1, 32768, 1024, 512);
  // P2: C2 = relu(C1 @ Wp2 + bp2)                     M=32768 N=1024 K=1024, g12 256x256 BK32
  g12_k<0, 0, true, bf16>
      <<<dim3(4, 128), 512, 0, stream>>>(C1, Wp2t, bp2, C2, 32768, 1024, 1024);
  // P3: logits = C2 @ Wp3 + bp3                       M=32768 N=64 K=1024, 128x64, D2
  pgemm_k<4, 2, 2, 2, 2, 0, 0, false, float>
      <<<dim3(1, 256), 256, 0, stream>>>(C2, Wp3t, bp3, logits, 32768, 64, 1024);
  // V1: hv = relu(joint @ Wv1 + biasV)                M=4096 N=1024 K=4096, 128x128, 4 waves, D2
  pgemm_k<4, 4, 2, 2, 2, 0, 0, true, bf16>
      <<<dim3(8, 32), 256, 0, stream>>>(joint, Wv1t, biasV, hv, 4096, 1024, 4096);
  // V2+V3 fused: value += relu(hv @ Wv2 + bv2) . Wv3  M=4096, 128x128, 4 waves, D2
  pgemm_k<4, 4, 2, 2, 2, 0, 0, true, bf16, 1>
      <<<dim3(8, 32), 256, 0, stream>>>(hv, Wv2t, bv2, (bf16*)nullptr, 4096, 1024, 1024, Wv3,
                                        value);
}

// Round 13
// 271.722 us; speedup vs baseline: 1.0525x; 1.0525x over previous
//
#include <hip/hip_runtime.h>
#include <hip/hip_bf16.h>

#define A_ 8
#define B_ 4096
#define OBS_ 512
#define ACT_ 64
#define H_ 1024
#define G_ 64
#define N_ 10000
#define E_ 40000

using bf16 = __hip_bfloat16;
typedef __attribute__((ext_vector_type(8))) short short8;
typedef __attribute__((ext_vector_type(4))) float f32x4;

__device__ __forceinline__ float wsum(float v) {
#pragma unroll
  for (int off = 32; off >= 1; off >>= 1) v += __shfl_xor(v, off, 64);
  return v;
}

__device__ __forceinline__ void storeC(float* p, float v) { *p = v; }
__device__ __forceinline__ void storeC(bf16* p, float v) { *p = __float2bfloat16(v); }

__device__ __forceinline__ unsigned short f2bu(float x) {
  bf16 h = __float2bfloat16(x);
  unsigned short u;
  __builtin_memcpy(&u, &h, 2);
  return u;
}

__device__ __forceinline__ void gload_lds16(const bf16* g, const void* lds_uniform) {
  __builtin_amdgcn_global_load_lds(
      (const __attribute__((address_space(1))) unsigned int*)g,
      (__attribute__((address_space(3))) unsigned int*)lds_uniform, 16, 0, 0);
}

template <int N>
__device__ __forceinline__ void waitvm() {
#define WV_CASE(n) if constexpr (N == n) asm volatile("s_waitcnt vmcnt(" #n ")" ::: "memory");
  WV_CASE(0) WV_CASE(1) WV_CASE(2) WV_CASE(3) WV_CASE(4) WV_CASE(5) WV_CASE(6) WV_CASE(7)
  WV_CASE(8) WV_CASE(9) WV_CASE(10) WV_CASE(12) WV_CASE(16)
  static_assert(N <= 16, "vmcnt too large");
#undef WV_CASE
}

// ======= prep_k: conv_joint (blocks 0-8191) + 5x wtrans (8192-14911) + gnn_l0 (14912-17411) ===
__global__ __launch_bounds__(256) void prep_k(
    const float* __restrict__ obs, bf16* __restrict__ joint,
    const float* __restrict__ Wp1, bf16* __restrict__ Wp1t,
    const float* __restrict__ Wp2, bf16* __restrict__ Wp2t,
    const float* __restrict__ Wp3, bf16* __restrict__ Wp3t,
    const float* __restrict__ Wv1, bf16* __restrict__ Wv1t,
    const float* __restrict__ Wv2, bf16* __restrict__ Wv2t,
    const int* __restrict__ node_types, const int* __restrict__ node_agents,
    const float* __restrict__ type_embed, const float* __restrict__ gagent_embed,
    const float* __restrict__ W_l0, const float* __restrict__ b_l0,
    const float* __restrict__ g_l0, const float* __restrict__ be_l0,
    float* __restrict__ h0, float* __restrict__ agg, float* __restrict__ deg) {
  __shared__ float shb[32 * 33];
  const int bid = blockIdx.x, tid = threadIdx.x;
  if (bid < 8192) {
    size_t i = ((size_t)bid * 256 + tid) * 8;
    int a = (int)(i >> 21);
    int rem = (int)(i & ((1u << 21) - 1));
    int b = rem >> 9, k = rem & 511;
    const float* p = obs + i;
    short8 o;
#pragma unroll
    for (int t = 0; t < 8; t++) o[t] = (short)f2bu(p[t]);
    *(short8*)(joint + (size_t)b * 4096 + a * 512 + k) = o;
  } else if (bid < 14912) {
    int b = bid - 8192;
    const float* W;
    bf16* Wt;
    int K, N;
    if (b < 512) { W = Wp1; Wt = Wp1t; K = 512; N = 1024; }
    else if (b < 1536) { W = Wp2; Wt = Wp2t; K = 1024; N = 1024; b -= 512; }
    else if (b < 1600) { W = Wp3; Wt = Wp3t; K = 1024; N = 64; b -= 1536; }
    else if (b < 5696) { W = Wv1; Wt = Wv1t; K = 4096; N = 1024; b -= 1600; }
    else { W = Wv2; Wt = Wv2t; K = 1024; N = 1024; b -= 5696; }
    int nx = N >> 5;
    int n0 = (b % nx) * 32, k0 = (b / nx) * 32;
    int tx = tid & 31, ty = tid >> 5;
    float(*t2)[33] = (float(*)[33])shb;
#pragma unroll
    for (int r = ty; r < 32; r += 8) t2[r][tx] = W[(size_t)(k0 + r) * N + n0 + tx];
    __syncthreads();
#pragma unroll
    for (int r = ty; r < 32; r += 8)
      Wt[(size_t)(n0 + r) * K + k0 + tx] = __float2bfloat16(t2[tx][r]);
  } else {
    int nb = bid - 14912;
    int w = tid >> 6, t = tid & 63;
    int n = nb * 4 + w;
    float* xx = shb + w * 64;
    int ty2 = node_types[n], ag = node_agents[n];
    xx[t] = (t < 32) ? type_embed[ty2 * 32 + t] : gagent_embed[ag * 32 + (t - 32)];
    agg[(size_t)n * 64 + t] = 0.f;
    if (t == 0) deg[n] = 0.f;
    __syncthreads();
    float acc = b_l0[t];
#pragma unroll 8
    for (int i = 0; i < 64; i++) acc += xx[i] * W_l0[i * 64 + t];
    acc = fmaxf(acc, 0.f);
    float m = wsum(acc) * (1.f / 64.f);
    float d = acc - m;
    float v = wsum(d * d) * (1.f / 64.f);
    h0[(size_t)n * 64 + t] = d * rsqrtf(v + 1e-5f) * g_l0[t] + be_l0[t];
  }
}

__global__ void edge_k(const int* __restrict__ edges, const float* __restrict__ h0,
                       float* __restrict__ agg, float* __restrict__ deg) {
  int idx = blockIdx.x * 256 + threadIdx.x;
  if (idx >= E_ * 64) return;
  int e = idx >> 6, c = idx & 63;
  int s = edges[e * 2 + 0], d = edges[e * 2 + 1];
  atomicAdd(&agg[(size_t)d * 64 + c], h0[(size_t)s * 64 + c]);
  atomicAdd(&agg[(size_t)s * 64 + c], h0[(size_t)d * 64 + c]);
  if (c == 0) { atomicAdd(&deg[d], 1.f); atomicAdd(&deg[s], 1.f); }
}

__global__ __launch_bounds__(256) void gnn_l1_k(
    const float* __restrict__ h0, const float* __restrict__ agg, const float* __restrict__ deg,
    const float* __restrict__ W, const float* __restrict__ b, const float* __restrict__ g,
    const float* __restrict__ be, float* __restrict__ h1) {
  __shared__ float x[4][128];
  int w = threadIdx.x >> 6, t = threadIdx.x & 63;
  int n = blockIdx.x * 4 + w;
  x[w][t] = h0[(size_t)n * 64 + t];
  x[w][64 + t] = agg[(size_t)n * 64 + t] / fmaxf(deg[n], 1.0f);
  __syncthreads();
  float acc = b[t];
#pragma unroll 8
  for (int i = 0; i < 128; i++) acc += x[w][i] * W[i * 64 + t];
  acc = fmaxf(acc, 0.f);
  float m = wsum(acc) * (1.f / 64.f);
  float d = acc - m;
  float v = wsum(d * d) * (1.f / 64.f);
  h1[(size_t)n * 64 + t] = d * rsqrtf(v + 1e-5f) * g[t] + be[t];
}

__global__ void colmean_k(const float* __restrict__ h1, float* __restrict__ meanv) {
  int c = blockIdx.x, t = threadIdx.x;
  float s = 0.f;
  for (int n = t; n < N_; n += 256) s += h1[(size_t)n * 64 + c];
  __shared__ float red[256];
  red[t] = s;
  __syncthreads();
  for (int off = 128; off >= 1; off >>= 1) {
    if (t < off) red[t] += red[t + off];
    __syncthreads();
  }
  if (t == 0) meanv[c] = red[0] / (float)N_;
}

__global__ void fused_bias_k(const float* __restrict__ meanv, const float* __restrict__ Wgp,
                             const float* __restrict__ bgp, const float* __restrict__ agent_embed,
                             const float* __restrict__ Wp1, const float* __restrict__ bp1,
                             const float* __restrict__ Wv1, const float* __restrict__ bv1,
                             const float* __restrict__ bv3,
                             float* __restrict__ biasA, float* __restrict__ biasV,
                             float* __restrict__ value) {
  __shared__ float ge[64];
  int t = threadIdx.x;
  int gidx = blockIdx.x * 256 + t;
  if (gidx < B_) value[gidx] = bv3[0];
  if (t < 64) {
    float s = bgp[t];
    for (int g2 = 0; g2 < 64; g2++) s += meanv[g2] * Wgp[g2 * 64 + t];
    ge[t] = s;
  }
  __syncthreads();
  int blk = blockIdx.x;
  if (blk < 32) {
    int idx = blk * 256 + t;
    int a = idx >> 10, o = idx & 1023;
    float s = bp1[o];
    for (int g2 = 0; g2 < 64; g2++) s += ge[g2] * Wp1[(size_t)(512 + g2) * 1024 + o];
    for (int e = 0; e < 16; e++) s += agent_embed[a * 16 + e] * Wp1[(size_t)(576 + e) * 1024 + o];
    biasA[idx] = s;
  } else {
    int o = (blk - 32) * 256 + t;
    float s = bv1[o];
    for (int g2 = 0; g2 < 64; g2++) s += ge[g2] * Wv1[(size_t)(4096 + g2) * 1024 + o];
    biasV[o] = s;
  }
}

// ======== g11_k: 256x256, BK=64, double buffer, 4 phases/K-tile, COUNTED vmcnt (R9-best) ====
#define BARR()                        \
  asm volatile("" ::: "memory");      \
  __builtin_amdgcn_s_barrier();       \
  asm volatile("" ::: "memory")

#define RD8(off) (*(const short8*)(sb + (off)))

#define MMQ(FI0)                                                                     \
  __builtin_amdgcn_s_setprio(1);                                                     \
  acc[FI0 + 0][0] = __builtin_amdgcn_mfma_f32_16x16x32_bf16(a0, b0, acc[FI0 + 0][0], 0, 0, 0); \
  acc[FI0 + 0][1] = __builtin_amdgcn_mfma_f32_16x16x32_bf16(a0, b1, acc[FI0 + 0][1], 0, 0, 0); \
  acc[FI0 + 0][2] = __builtin_amdgcn_mfma_f32_16x16x32_bf16(a0, b2, acc[FI0 + 0][2], 0, 0, 0); \
  acc[FI0 + 0][3] = __builtin_amdgcn_mfma_f32_16x16x32_bf16(a0, b3, acc[FI0 + 0][3], 0, 0, 0); \
  acc[FI0 + 1][0] = __builtin_amdgcn_mfma_f32_16x16x32_bf16(a1, b0, acc[FI0 + 1][0], 0, 0, 0); \
  acc[FI0 + 1][1] = __builtin_amdgcn_mfma_f32_16x16x32_bf16(a1, b1, acc[FI0 + 1][1], 0, 0, 0); \
  acc[FI0 + 1][2] = __builtin_amdgcn_mfma_f32_16x16x32_bf16(a1, b2, acc[FI0 + 1][2], 0, 0, 0); \
  acc[FI0 + 1][3] = __builtin_amdgcn_mfma_f32_16x16x32_bf16(a1, b3, acc[FI0 + 1][3], 0, 0, 0); \
  acc[FI0 + 2][0] = __builtin_amdgcn_mfma_f32_16x16x32_bf16(a2, b0, acc[FI0 + 2][0], 0, 0, 0); \
  acc[FI0 + 2][1] = __builtin_amdgcn_mfma_f32_16x16x32_bf16(a2, b1, acc[FI0 + 2][1], 0, 0, 0); \
  acc[FI0 + 2][2] = __builtin_amdgcn_mfma_f32_16x16x32_bf16(a2, b2, acc[FI0 + 2][2], 0, 0, 0); \
  acc[FI0 + 2][3] = __builtin_amdgcn_mfma_f32_16x16x32_bf16(a2, b3, acc[FI0 + 2][3], 0, 0, 0); \
  acc[FI0 + 3][0] = __builtin_amdgcn_mfma_f32_16x16x32_bf16(a3, b0, acc[FI0 + 3][0], 0, 0, 0); \
  acc[FI0 + 3][1] = __builtin_amdgcn_mfma_f32_16x16x32_bf16(a3, b1, acc[FI0 + 3][1], 0, 0, 0); \
  acc[FI0 + 3][2] = __builtin_amdgcn_mfma_f32_16x16x32_bf16(a3, b2, acc[FI0 + 3][2], 0, 0, 0); \
  acc[FI0 + 3][3] = __builtin_amdgcn_mfma_f32_16x16x32_bf16(a3, b3, acc[FI0 + 3][3], 0, 0, 0); \
  __builtin_amdgcn_s_setprio(0)

template <int AMODE, int BIASMODE, bool RELU, typename TC>
__launch_bounds__(512, 1)
__global__ void g11_k(const bf16* __restrict__ Ap, const bf16* __restrict__ Bt,
                      const float* __restrict__ biasp, TC* __restrict__ Cp,
                      int M, int N, int K) {
  constexpr int SBUF = 65536;
  __shared__ char smem[2 * SBUF];

  const int tid = threadIdx.x;
  const int wid = tid >> 6, lane = tid & 63;
  const int wm = wid >> 2, wn = wid & 3;
  const int l15 = lane & 15;

  const int nwg = gridDim.x * gridDim.y;
  int fid = blockIdx.y * gridDim.x + blockIdx.x;
  int swz = (fid & 7) * (nwg >> 3) + (fid >> 3);
  const int m0 = (swz / gridDim.x) * 256;
  const int n0 = (swz % gridDim.x) * 256;

  f32x4 acc[8][4];
#pragma unroll
  for (int i = 0; i < 8; i++)
#pragma unroll
    for (int j = 0; j < 4; j++) acc[i][j] = (f32x4){0.f, 0.f, 0.f, 0.f};

  const bf16* pg[8];
  {
    int srow = tid >> 3;
    int c = (tid & 7) ^ (srow & 7);
#pragma unroll
    for (int g = 0; g < 4; ++g) {
      int r = m0 + g * 64 + srow;
      if (AMODE == 0)
        pg[g] = Ap + (size_t)r * K + c * 8;
      else
        pg[g] = Ap + (((size_t)(r & (B_ - 1))) << 12) + ((size_t)(r >> 12) << 9) + c * 8;
    }
#pragma unroll
    for (int g = 4; g < 8; ++g) {
      int r = n0 + (g - 4) * 64 + srow;
      pg[g] = Bt + (size_t)r * K + c * 8;
    }
  }

  const int slot0 = (lane >> 4) ^ (l15 & 7);
  const int aof0 = (wm * 128 + l15) * 128 + slot0 * 16;
  const int bof0 = 32768 + (wn * 64 + l15) * 128 + slot0 * 16;
  const int aof1 = aof0 ^ 64;
  const int bof1 = bof0 ^ 64;

#define STG(g, buf)                                                    \
  {                                                                    \
    gload_lds16(pg[g], smem + (buf) * SBUF + (g) * 8192 + wid * 1024); \
    pg[g] += 64;                                                       \
  }

  STG(0, 0) STG(2, 0) STG(4, 0) STG(5, 0) STG(6, 0) STG(7, 0) STG(1, 0) STG(3, 0)
  waitvm<0>();
  BARR();

  const int nt = K >> 6;
  for (int t = 0; t < nt; ++t) {
    const int cb = t & 1, ob = cb ^ 1;
    const bool last = (t == nt - 1);
    const char* sb = smem + cb * SBUF;
    short8 a0, a1, a2, a3, b0, b1, b2, b3;
    a0 = RD8(aof0 + 0 * 2048); a1 = RD8(aof0 + 1 * 2048);
    a2 = RD8(aof0 + 2 * 2048); a3 = RD8(aof0 + 3 * 2048);
    b0 = RD8(bof0 + 0 * 2048); b1 = RD8(bof0 + 1 * 2048);
    b2 = RD8(bof0 + 2 * 2048); b3 = RD8(bof0 + 3 * 2048);
    if (!last) { STG(0, ob) STG(2, ob) }
    BARR();
    MMQ(0);
    if (last) waitvm<0>(); else waitvm<2>();
    BARR();
    a0 = RD8(aof0 + 4 * 2048); a1 = RD8(aof0 + 5 * 2048);
    a2 = RD8(aof0 + 6 * 2048); a3 = RD8(aof0 + 7 * 2048);
    if (!last) { STG(4, ob) STG(5, ob) }
    BARR();
    MMQ(4);
    BARR();
    a0 = RD8(aof1 + 0 * 2048); a1 = RD8(aof1 + 1 * 2048);
    a2 = RD8(aof1 + 2 * 2048); a3 = RD8(aof1 + 3 * 2048);
    b0 = RD8(bof1 + 0 * 2048); b1 = RD8(bof1 + 1 * 2048);
    b2 = RD8(bof1 + 2 * 2048); b3 = RD8(bof1 + 3 * 2048);
    if (!last) { STG(6, ob) STG(7, ob) }
    BARR();
    MMQ(0);
    BARR();
    a0 = RD8(aof1 + 4 * 2048); a1 = RD8(aof1 + 5 * 2048);
    a2 = RD8(aof1 + 6 * 2048); a3 = RD8(aof1 + 7 * 2048);
    if (!last) { STG(1, ob) STG(3, ob) }
    BARR();
    MMQ(4);
    if (!last) waitvm<2>(); else waitvm<0>();
    BARR();
  }
#undef STG

#pragma unroll
  for (int i = 0; i < 8; ++i) {
    int rb = m0 + wm * 128 + i * 16 + (lane >> 4) * 4;
#pragma unroll
    for (int j = 0; j < 4; ++j) {
      int col = n0 + wn * 64 + j * 16 + l15;
#pragma unroll
      for (int r = 0; r < 4; r++) {
        int row = rb + r;
        float bias = (BIASMODE == 0) ? biasp[col] : biasp[((row >> 12) << 10) + col];
        float v = acc[i][j][r] + bias;
        if (RELU) v = fmaxf(v, 0.f);
        storeC(&Cp[(size_t)row * N + col], v);
      }
    }
  }
}

// ---------------- MFMA GEMM body (device fn): DEPTH-deep pipeline, counted vmcnt ------------
// VOUT=1: accumulate value[row] += relu(C[row,:]+bias) . Wv3 instead of storing C
template <int FM, int FN, int WAVES_M, int WAVES_N, int DEPTH, int AMODE, int BIASMODE, bool RELU,
          typename TC, int VOUT>
__device__ void pgemm_dev(char* smem, const bf16* __restrict__ Ap, const bf16* __restrict__ Bt,
                          const float* __restrict__ biasp, TC* __restrict__ Cp,
                          int M, int N, int K, const float* __restrict__ Wv3,
                          float* __restrict__ vout, int fid, int gx, int nwg) {
  constexpr int NTHR = WAVES_M * WAVES_N * 64;
  constexpr int AR = WAVES_M * FM * 16;
  constexpr int BR = WAVES_N * FN * 16;
  constexpr int RPG = NTHR / 4;
  constexpr int AG = AR / RPG;
  constexpr int BG = BR / RPG;
  constexpr int G = AG + BG;
  constexpr int GRP = NTHR * 16;
  constexpr int ABYTES = AR * 64;
  constexpr int SBUF = (AR + BR) * 64;
  constexpr int NB = DEPTH + 1;

  const int tid = threadIdx.x;
  const int wid = tid >> 6, lane = tid & 63;
  const int wm = wid / WAVES_N, wn = wid % WAVES_N;
  const int l15 = lane & 15;

  int swz = (fid & 7) * (nwg >> 3) + (fid >> 3);
  const int m0 = (swz / gx) * AR;
  const int n0 = (swz % gx) * BR;

  f32x4 acc[FM][FN];
#pragma unroll
  for (int i = 0; i < FM; i++)
#pragma unroll
    for (int j = 0; j < FN; j++) acc[i][j] = (f32x4){0.f, 0.f, 0.f, 0.f};

  const bf16* pa[AG];
  const bf16* pb[BG];
  {
    int row = tid >> 2;
    int c = (tid & 3) ^ ((tid >> 3) & 3);
#pragma unroll
    for (int q = 0; q < AG; ++q) {
      int r = m0 + q * RPG + row;
      if (AMODE == 0)
        pa[q] = Ap + (size_t)r * K + c * 8;
      else
        pa[q] = Ap + (((size_t)(r & (B_ - 1))) << 12) + ((size_t)(r >> 12) << 9) + c * 8;
    }
#pragma unroll
    for (int q = 0; q < BG; ++q) {
      int r = n0 + q * RPG + row;
      pb[q] = Bt + (size_t)r * K + c * 8;
    }
  }

  const int cA = (lane >> 4) ^ ((l15 >> 1) & 3);
  const int offA0 = (wm * FM * 16 + l15) * 64 + cA * 16;
  const int offB0 = ABYTES + (wn * FN * 16 + l15) * 64 + cA * 16;

  auto stage = [&](int buf) {
    char* base = smem + buf * SBUF;
#pragma unroll
    for (int q = 0; q < AG; ++q) {
      gload_lds16(pa[q], base + q * GRP + wid * 1024);
      pa[q] += 32;
    }
#pragma unroll
    for (int q = 0; q < BG; ++q) {
      gload_lds16(pb[q], base + ABYTES + q * GRP + wid * 1024);
      pb[q] += 32;
    }
  };

  auto comp = [&](int buf) {
    const char* sb = smem + buf * SBUF;
    short8 bfr[FN];
#pragma unroll
    for (int j = 0; j < FN; ++j) bfr[j] = *(const short8*)(sb + offB0 + j * 1024);
    constexpr int FH = (FM > 4) ? FM / 2 : FM;
#pragma unroll
    for (int h = 0; h < FM / FH; ++h) {
      short8 afr[FH];
#pragma unroll
      for (int i = 0; i < FH; ++i) afr[i] = *(const short8*)(sb + offA0 + (h * FH + i) * 1024);
      __builtin_amdgcn_s_setprio(1);
#pragma unroll
      for (int i = 0; i < FH; ++i)
#pragma unroll
        for (int j = 0; j < FN; ++j)
          acc[h * FH + i][j] =
              __builtin_amdgcn_mfma_f32_16x16x32_bf16(afr[i], bfr[j], acc[h * FH + i][j], 0, 0, 0);
      __builtin_amdgcn_s_setprio(0);
    }
  };

  const int nt = K >> 5;
#pragma unroll
  for (int q = 0; q < DEPTH; ++q) stage(q);
  int cbuf = 0, sbi = DEPTH;
  for (int T = 0; T < nt - DEPTH; ++T) {
    stage(sbi);
    if (++sbi == NB) sbi = 0;
    waitvm<DEPTH * G>();
    __builtin_amdgcn_s_barrier();
    asm volatile("" ::: "memory");
    comp(cbuf);
    if (++cbuf == NB) cbuf = 0;
    asm volatile("" ::: "memory");
    __builtin_amdgcn_s_barrier();
  }
#define DRAIN(d)                       \
  {                                    \
    waitvm<(d) * G>();                 \
    __builtin_amdgcn_s_barrier();      \
    asm volatile("" ::: "memory");     \
    comp(cbuf);                        \
    if (++cbuf == NB) cbuf = 0;        \
    asm volatile("" ::: "memory");     \
  }
  if constexpr (DEPTH == 4) { DRAIN(3) DRAIN(2) }
  DRAIN(1)
  DRAIN(0)
#undef DRAIN

#pragma unroll
  for (int i = 0; i < FM; ++i) {
    int rb = m0 + wm * FM * 16 + i * 16 + (lane >> 4) * 4;
    if constexpr (VOUT) {
#pragma unroll
      for (int r = 0; r < 4; r++) {
        int row = rb + r;
        float s = 0.f;
#pragma unroll
        for (int j = 0; j < FN; ++j) {
          int col = n0 + wn * FN * 16 + j * 16 + l15;
          float v = acc[i][j][r] + biasp[col];
          if (RELU) v = fmaxf(v, 0.f);
          s += v * Wv3[col];
        }
        s += __shfl_xor(s, 1, 64);
        s += __shfl_xor(s, 2, 64);
        s += __shfl_xor(s, 4, 64);
        s += __shfl_xor(s, 8, 64);
        if (l15 == 0) atomicAdd(&vout[row], s);
      }
    } else {
#pragma unroll
      for (int j = 0; j < FN; ++j) {
        int col = n0 + wn * FN * 16 + j * 16 + l15;
#pragma unroll
        for (int r = 0; r < 4; r++) {
          int row = rb + r;
          float bias = (BIASMODE == 0) ? biasp[col] : biasp[((row >> 12) << 10) + col];
          float v = acc[i][j][r] + bias;
          if (RELU) v = fmaxf(v, 0.f);
          storeC(&Cp[(size_t)row * N + col], v);
        }
      }
    }
  }
}

// wrapper (V1)
template <int FM, int FN, int WAVES_M, int WAVES_N, int DEPTH, int AMODE, int BIASMODE, bool RELU,
          typename TC, int VOUT = 0>
__launch_bounds__(WAVES_M * WAVES_N * 64, 2)
__global__ void pgemm_k(const bf16* __restrict__ Ap, const bf16* __restrict__ Bt,
                        const float* __restrict__ biasp, TC* __restrict__ Cp,
                        int M, int N, int K,
                        const float* __restrict__ Wv3 = nullptr,
                        float* __restrict__ vout = nullptr) {
  constexpr int SBUF = ((WAVES_M * FM * 16) + (WAVES_N * FN * 16)) * 64;
  __shared__ char smem[(DEPTH + 1) * SBUF];
  int fid = blockIdx.y * gridDim.x + blockIdx.x;
  pgemm_dev<FM, FN, WAVES_M, WAVES_N, DEPTH, AMODE, BIASMODE, RELU, TC, VOUT>(
      smem, Ap, Bt, biasp, Cp, M, N, K, Wv3, vout, fid, gridDim.x, gridDim.x * gridDim.y);
}

// merged P3 (blocks 0-255) + V2V3 (blocks 256-511); both 256-thr pgemm instances
__launch_bounds__(256, 2)
__global__ void pv_k(const bf16* __restrict__ C2, const bf16* __restrict__ Wp3t,
                     const float* __restrict__ bp3, float* __restrict__ logits,
                     const bf16* __restrict__ hv, const bf16* __restrict__ Wv2t,
                     const float* __restrict__ bv2, const float* __restrict__ Wv3,
                     float* __restrict__ value) {
  __shared__ char smem[49152];  // max of the two branches' (DEPTH+1)*SBUF: 36 KB / 48 KB
  if (blockIdx.x < 256) {
    // P3: logits = C2 @ Wp3 + bp3; M=32768 N=64 K=1024; tile 128x64; grid-equiv (1,256)
    pgemm_dev<4, 2, 2, 2, 2, 0, 0, false, float, 0>(
        smem, C2, Wp3t, bp3, logits, 32768, 64, 1024, nullptr, nullptr, blockIdx.x, 1, 256);
  } else {
    // V2+V3: value += relu(hv @ Wv2 + bv2) . Wv3; M=4096 N=1024 K=1024; tile 128x128; (8,32)
    pgemm_dev<4, 4, 2, 2, 2, 0, 0, true, bf16, 1>(
        smem, hv, Wv2t, bv2, (bf16*)nullptr, 4096, 1024, 1024, Wv3, value, blockIdx.x - 256, 8,
        256);
  }
}

extern "C" void kernel_launch(void* const* d_in, const int* in_sizes, int n_in,
                              void* d_out, int out_size, void* d_ws, size_t ws_size,
                              hipStream_t stream) {
  const float* obs = (const float*)d_in[0];
  const int* node_types = (const int*)d_in[1];
  const int* node_agents = (const int*)d_in[2];
  const int* edges = (const int*)d_in[3];
  const float* type_embed = (const float*)d_in[4];
  const float* gagent_embed = (const float*)d_in[5];
  const float* W_l0 = (const float*)d_in[6];
  const float* b_l0 = (const float*)d_in[7];
  const float* g_l0 = (const float*)d_in[8];
  const float* be_l0 = (const float*)d_in[9];
  const float* W_l1 = (const float*)d_in[10];
  const float* b_l1 = (const float*)d_in[11];
  const float* g_l1 = (const float*)d_in[12];
  const float* be_l1 = (const float*)d_in[13];
  const float* W_gp = (const float*)d_in[14];
  const float* b_gp = (const float*)d_in[15];
  const float* agent_embed = (const float*)d_in[16];
  const float* Wp1 = (const float*)d_in[17];
  const float* bp1 = (const float*)d_in[18];
  const float* Wp2 = (const float*)d_in[19];
  const float* bp2 = (const float*)d_in[20];
  const float* Wp3 = (const float*)d_in[21];
  const float* bp3 = (const float*)d_in[22];
  const float* Wv1 = (const float*)d_in[23];
  const float* bv1 = (const float*)d_in[24];
  const float* Wv2 = (const float*)d_in[25];
  const float* bv2 = (const float*)d_in[26];
  const float* Wv3 = (const float*)d_in[27];
  const float* bv3 = (const float*)d_in[28];

  char* wsp = (char*)d_ws;
  auto alloc = [&](size_t bytes) {
    char* p = wsp;
    wsp += (bytes + 255) & ~(size_t)255;
    return p;
  };
  float* h0 = (float*)alloc((size_t)N_ * 64 * 4);
  float* agg = (float*)alloc((size_t)N_ * 64 * 4);
  float* deg = (float*)alloc((size_t)N_ * 4);
  float* h1 = (float*)alloc((size_t)N_ * 64 * 4);
  float* meanv = (float*)alloc(64 * 4);
  float* biasA = (float*)alloc(8 * 1024 * 4);
  float* biasV = (float*)alloc(1024 * 4);
  bf16* joint = (bf16*)alloc((size_t)4096 * 4096 * 2);
  bf16* Wp1t = (bf16*)alloc((size_t)1024 * 512 * 2);
  bf16* Wp2t = (bf16*)alloc((size_t)1024 * 1024 * 2);
  bf16* Wp3t = (bf16*)alloc((size_t)64 * 1024 * 2);
  bf16* Wv1t = (bf16*)alloc((size_t)1024 * 4096 * 2);
  bf16* Wv2t = (bf16*)alloc((size_t)1024 * 1024 * 2);
  bf16* C1 = (bf16*)alloc((size_t)32768 * 1024 * 2);
  bf16* C2 = (bf16*)alloc((size_t)32768 * 1024 * 2);
  bf16* hv = (bf16*)alloc((size_t)4096 * 1024 * 2);

  float* logits = (float*)d_out;
  float* value = (float*)d_out + (size_t)A_ * B_ * ACT_;

  // prep: conv_joint + 5x wtrans + gnn_l0 (co-scheduled in one launch)
  prep_k<<<17412, 256, 0, stream>>>(obs, joint, Wp1, Wp1t, Wp2, Wp2t, Wp3, Wp3t, Wv1, Wv1t, Wv2,
                                    Wv2t, node_types, node_agents, type_embed, gagent_embed, W_l0,
                                    b_l0, g_l0, be_l0, h0, agg, deg);
  edge_k<<<(E_ * 64) / 256, 256, 0, stream>>>(edges, h0, agg, deg);
  gnn_l1_k<<<N_ / 4, 256, 0, stream>>>(h0, agg, deg, W_l1, b_l1, g_l1, be_l1, h1);
  colmean_k<<<64, 256, 0, stream>>>(h1, meanv);
  fused_bias_k<<<36, 256, 0, stream>>>(meanv, W_gp, b_gp, agent_embed, Wp1, bp1, Wv1, bv1, bv3,
                                       biasA, biasV, value);

  // P1: C1 = relu(obs2d @ Wp1[0:512] + biasA[agent])  M=32768 N=1024 K=512, g11 256x256 BK64
  g11_k<1, 1, true, bf16>
      <<<dim3(4, 128), 512, 0, stream>>>(joint, Wp1t, biasA, C1, 32768, 1024, 512);
  // P2: C2 = relu(C1 @ Wp2 + bp2)                     M=32768 N=1024 K=1024, g11 256x256 BK64
  g11_k<0, 0, true, bf16>
      <<<dim3(4, 128), 512, 0, stream>>>(C1, Wp2t, bp2, C2, 32768, 1024, 1024);
  // V1: hv = relu(joint @ Wv1 + biasV)                M=4096 N=1024 K=4096, 128x128, 4 waves, D2
  pgemm_k<4, 4, 2, 2, 2, 0, 0, true, bf16>
      <<<dim3(8, 32), 256, 0, stream>>>(joint, Wv1t, biasV, hv, 4096, 1024, 4096);
  // merged: P3 (logits = C2 @ Wp3 + bp3) + V2V3 (value += relu(hv@Wv2+bv2).Wv3)
  pv_k<<<512, 256, 0, stream>>>(C2, Wp3t, bp3, logits, hv, Wv2t, bv2, Wv3, value);
}